// Round 10
// baseline (305.628 us; speedup 1.0000x reference)
//
#include <hip/hip_runtime.h>

typedef float  f32x4 __attribute__((ext_vector_type(4)));
typedef short  s16x8 __attribute__((ext_vector_type(8)));
typedef short  s16x4 __attribute__((ext_vector_type(4)));
typedef unsigned short u16;

#define HDIM 1024
#define BATCH 32
#define SEQ 2048
#define NROWS (BATCH*SEQ)   // 65536

// k_score: 256x256 tile, BK=64 (2 ks-planes of 32), 8 waves (2M x 4N), 512 thr
#define NTILES 16           // K / 64
#define PLANE 4096          // elems per LDS plane: 128 rows x 32 (64B rows)

#define GLD16(gp, lp) __builtin_amdgcn_global_load_lds( \
    (const __attribute__((address_space(1))) void*)(gp), \
    (__attribute__((address_space(3))) void*)(lp), 16, 0, 0)

#define VMCNT(n) asm volatile("s_waitcnt vmcnt(" #n ")" ::: "memory")
#define LGKM0    asm volatile("s_waitcnt lgkmcnt(0)" ::: "memory")
#define BARRIER  asm volatile("s_barrier" ::: "memory")
#define SCHEDB   __builtin_amdgcn_sched_barrier(0)

__device__ __forceinline__ u16 f2bf(float f){
    unsigned u = __float_as_uint(f);
    u = u + 0x7FFFu + ((u >> 16) & 1u);   // RNE
    return (u16)(u >> 16);
}

__device__ __forceinline__ float tanh_fast(float x){
    float e = __builtin_amdgcn_exp2f(x * 2.885390082f);
    return 1.0f - 2.0f * __builtin_amdgcn_rcpf(e + 1.0f);
}

// ---------------- keys fp32 -> bf16, coalesced (~61 us HBM floor) ----------------
__global__ __launch_bounds__(256) void k_cvt(const float* __restrict__ in,
                                             u16* __restrict__ out){
    size_t base = (size_t)blockIdx.x * 256 + threadIdx.x;   // 524288 threads
    const f32x4* ip = (const f32x4*)in;
    s16x4* op = (s16x4*)out;
#pragma unroll 4
    for (int i = 0; i < 32; ++i){
        size_t c = base + (size_t)i * 524288;
        f32x4 v = ip[c];
        s16x4 o;
        o[0] = (short)f2bf(v.x); o[1] = (short)f2bf(v.y);
        o[2] = (short)f2bf(v.z); o[3] = (short)f2bf(v.w);
        op[c] = o;
    }
}

// ---------------- W1 -> W1T (bf16, transposed) -----------------------------------
__global__ __launch_bounds__(256) void k_w1t(const float* __restrict__ W1,
                                             u16* __restrict__ W1T){
    __shared__ u16 t[64][65];
    int blk = blockIdx.x;
    int bh = blk >> 4, bd = blk & 15;
    int h0 = bh * 64, d0 = bd * 64;
    int tid = threadIdx.x;
    int lh = tid >> 4, ld = (tid & 15) * 4;
#pragma unroll
    for (int i = 0; i < 4; ++i){
        int hh = lh + i * 16;
        f32x4 v = *(const f32x4*)&W1[(size_t)(h0 + hh) * HDIM + d0 + ld];
        t[hh][ld + 0] = f2bf(v.x);
        t[hh][ld + 1] = f2bf(v.y);
        t[hh][ld + 2] = f2bf(v.z);
        t[hh][ld + 3] = f2bf(v.w);
    }
    __syncthreads();
    int wv = tid >> 6, ln = tid & 63;
#pragma unroll
    for (int i = 0; i < 16; ++i){
        int d = i * 4 + wv;
        W1T[(size_t)(d0 + d) * HDIM + h0 + ln] = t[ln][d];
    }
}

// ---------------- qproj: 512 blocks, 4 h-quarter partials + LDS reduce -----------
__global__ __launch_bounds__(256) void k_qproj(const float* __restrict__ query,
                                               const float* __restrict__ W2,
                                               float* __restrict__ qproj){
    int b = blockIdx.x >> 4, dc = blockIdx.x & 15;
    int t = threadIdx.x;
    int dl = t & 63, hq = t >> 6;
    int d = dc * 64 + dl;
    const float* q = query + (size_t)b * HDIM;
    float acc = 0.f;
#pragma unroll 8
    for (int h = hq * 256; h < hq * 256 + 256; ++h)
        acc += q[h] * W2[(size_t)h * HDIM + d];
    __shared__ float red[4][64];
    red[hq][dl] = acc;
    __syncthreads();
    if (hq == 0)
        qproj[(size_t)b * HDIM + d] = red[0][dl] + red[1][dl] + red[2][dl] + red[3][dl];
}

// ---------------- scores GEMM: R3 champion loop shape at BK=64 -------------------
// LDS planes [buf(2)][half(2)][ks(2)] of 128x32 (R4 layout, refcheck'd), 128 KB.
// Per K-tile: {24 ds_read || 64 MFMA} -> LGKM0 -> BARRIER -> stage(t+2, 8 loads)
// -> VMCNT(8) (tile t+1 landed; t+2 in flight) -> BARRIER. Exactly R3's two-
// barrier counted-vmcnt pattern (173 us champion), tiles halved 32 -> 16.
__global__ __launch_bounds__(512, 2) void k_score(const u16* __restrict__ keysbf,
                                                  const u16* __restrict__ W1T,
                                                  const float* __restrict__ qproj,
                                                  const float* __restrict__ V,
                                                  float* __restrict__ spart){
    int bid = blockIdx.x;
    int lid = (bid & 7) * 128 + (bid >> 3);   // XCD swizzle; 4 nt of one mt per XCD
    int mt  = lid >> 2;           // 0..255
    int nt  = lid & 3;            // 0..3

    __shared__ u16 As[8 * PLANE];   // 64 KB
    __shared__ u16 Bs[8 * PLANE];   // 64 KB

    int tid  = threadIdx.x;
    int lane = tid & 63, wave = tid >> 6;
    int wm = wave >> 2, wn = wave & 3;
    int g  = lane >> 4, q = lane & 15;

    // staging coords (pre-swizzled global source, linear LDS dest) — refcheck'd R4
    int sr = tid >> 2, sl = tid & 3;
    int ch = sl ^ ((sr >> 1) & 3);
    const u16* abase = keysbf + (size_t)(mt * 256 + sr) * HDIM + ch * 8;
    const u16* bbase = W1T    + (size_t)(nt * 256 + sr) * HDIM + ch * 8;
    int sdst = tid * 8;

    // plane index = (buf<<2) | (half<<1) | ks
    auto stage = [&](int buf, int t){
#pragma unroll
        for (int ks = 0; ks < 2; ++ks){
            int ko = t * 64 + ks * 32;
            GLD16(abase + ko,              &As[((buf << 2) | ks) * PLANE + sdst]);
            GLD16(abase + ko + 128 * HDIM, &As[((buf << 2) | 2 | ks) * PLANE + sdst]);
            GLD16(bbase + ko,              &Bs[((buf << 2) | ks) * PLANE + sdst]);
            GLD16(bbase + ko + 128 * HDIM, &Bs[((buf << 2) | 2 | ks) * PLANE + sdst]);
        }
    };

    // read offsets (swizzled, lane-constant; refcheck'd R4)
    int rslot = (g ^ ((q >> 1) & 3)) * 8;
    int arow  = q * 32 + rslot;                        // + m*512
    int brow  = ((wn & 1) * 64 + q) * 32 + rslot;      // + n*512

    f32x4 acc[8][4];
#pragma unroll
    for (int m = 0; m < 8; ++m)
#pragma unroll
        for (int n = 0; n < 4; ++n) acc[m][n] = 0.f;

    // prologue: stage tiles 0,1 (16 loads); tile 0 landed
    stage(0, 0);
    stage(1, 1);
    VMCNT(8);
    SCHEDB;
    BARRIER;
    SCHEDB;

    for (int t = 0; t < NTILES; ++t){
        int c = t & 1;
        int tn = (t + 2 < NTILES) ? t + 2 : NTILES - 1;   // dummy re-stage at tail
        const u16* Ap = &As[((c << 2) | (wm << 1)) * PLANE];
        const u16* Bp = &Bs[((c << 2) | ((wn >> 1) << 1)) * PLANE];
        s16x8 af[8], bq[4];

#pragma unroll
        for (int ks = 0; ks < 2; ++ks){
            const u16* Aps = Ap + ks * PLANE;
            const u16* Bps = Bp + ks * PLANE;
#pragma unroll
            for (int m = 0; m < 8; ++m) af[m] = *(const s16x8*)&Aps[arow + m * 512];
#pragma unroll
            for (int n = 0; n < 4; ++n) bq[n] = *(const s16x8*)&Bps[brow + n * 512];
            __builtin_amdgcn_s_setprio(1);
#pragma unroll
            for (int m = 0; m < 8; ++m)
#pragma unroll
                for (int n = 0; n < 4; ++n)
                    acc[m][n] = __builtin_amdgcn_mfma_f32_16x16x32_bf16(af[m], bq[n], acc[m][n], 0, 0, 0);
            __builtin_amdgcn_s_setprio(0);
        }

        SCHEDB;
        LGKM0;          // this wave's ds_reads of buf c complete
        BARRIER;        // all waves done reading buf c
        SCHEDB;
        stage(c, tn);   // overwrite buf c with tile t+2 (dummy at tail)
        VMCNT(8);       // tile t+1 (issued last iter) fully landed; t+2 in flight
        SCHEDB;
        BARRIER;        // all waves agree buf c^1 is ready
        SCHEDB;
    }
    VMCNT(0);   // drain dummy stages before LDS dealloc

    // ---- epilogue: spart[R][nt*4+wn] over this wave's 64 d-cols ----
    int b_idx = mt >> 3;
    float Vn[4], Qn[4];
#pragma unroll
    for (int n = 0; n < 4; ++n){
        int D = nt * 256 + wn * 64 + n * 16 + q;
        Vn[n] = V[D];
        Qn[n] = qproj[(size_t)b_idx * HDIM + D];
    }
#pragma unroll
    for (int m = 0; m < 8; ++m){
#pragma unroll
        for (int r = 0; r < 4; ++r){
            float s = 0.f;
#pragma unroll
            for (int n = 0; n < 4; ++n){
                float x = acc[m][n][r] + Qn[n];
                s += Vn[n] * tanh_fast(x);
            }
            s += __shfl_xor(s, 1);
            s += __shfl_xor(s, 2);
            s += __shfl_xor(s, 4);
            s += __shfl_xor(s, 8);
            if (q == 0){
                int R = mt * 256 + wm * 128 + m * 16 + g * 4 + r;
                spart[(size_t)R * 16 + nt * 4 + wn] = s;
            }
        }
    }
}

// ---------------- softmax over S per batch ---------------------------------------
__global__ __launch_bounds__(256) void k_softmax(const float* __restrict__ spart,
                                                 const int* __restrict__ mask,
                                                 float* __restrict__ attn){
    int b = blockIdx.x;
    int tid = threadIdx.x;
    int lane = tid & 63, wv = tid >> 6;
    __shared__ float redmx[4];
    __shared__ float redsm[4];

    float sc[8];
#pragma unroll
    for (int i = 0; i < 8; ++i){
        int s = i * 256 + tid;
        const f32x4* p = (const f32x4*)&spart[(size_t)(b * SEQ + s) * 16];
        f32x4 v0 = p[0], v1 = p[1], v2 = p[2], v3 = p[3];
        float sum = (v0.x + v0.y + v0.z + v0.w) + (v1.x + v1.y + v1.z + v1.w)
                  + (v2.x + v2.y + v2.z + v2.w) + (v3.x + v3.y + v3.z + v3.w);
        sc[i] = (mask[b * SEQ + s] == 0) ? -1e9f : sum;
    }
    float mx = sc[0];
#pragma unroll
    for (int i = 1; i < 8; ++i) mx = fmaxf(mx, sc[i]);
#pragma unroll
    for (int o = 32; o >= 1; o >>= 1) mx = fmaxf(mx, __shfl_xor(mx, o));
    if (lane == 0) redmx[wv] = mx;
    __syncthreads();
    mx = fmaxf(fmaxf(redmx[0], redmx[1]), fmaxf(redmx[2], redmx[3]));

    float ex[8], ssum = 0.f;
#pragma unroll
    for (int i = 0; i < 8; ++i){
        ex[i] = __builtin_amdgcn_exp2f((sc[i] - mx) * 1.4426950408889634f);
        ssum += ex[i];
    }
#pragma unroll
    for (int o = 32; o >= 1; o >>= 1) ssum += __shfl_xor(ssum, o);
    if (lane == 0) redsm[wv] = ssum;
    __syncthreads();
    ssum = redsm[0] + redsm[1] + redsm[2] + redsm[3];
    float inv = 1.0f / ssum;
#pragma unroll
    for (int i = 0; i < 8; ++i)
        attn[(size_t)b * SEQ + i * 256 + tid] = ex[i] * inv;
}

// ---------------- context partials: masked rows skipped (wave-uniform) -----------
__global__ __launch_bounds__(256) void k_ctxpart(const u16* __restrict__ keysbf,
                                                 const float* __restrict__ attn,
                                                 float* __restrict__ cpart){
    int blk = blockIdx.x;                 // 1024 blocks
    int b = blk >> 5, scn = blk & 31;     // 64 rows each
    int t = threadIdx.x;
    f32x4 acc = 0.f;
    const s16x4* kp = (const s16x4*)(keysbf + (size_t)(b * SEQ + scn * 64) * HDIM) + t;
    const float* ap = attn + (size_t)b * SEQ + scn * 64;
    for (int s = 0; s < 64; ++s){
        float a = ap[s];
        if (a == 0.f) continue;           // masked: attn exactly 0; branch is
                                          // wave-uniform (a same for all lanes)
        s16x4 kv = kp[(size_t)s * 256];
        f32x4 kf;
        kf.x = __uint_as_float((unsigned)(unsigned short)kv[0] << 16);
        kf.y = __uint_as_float((unsigned)(unsigned short)kv[1] << 16);
        kf.z = __uint_as_float((unsigned)(unsigned short)kv[2] << 16);
        kf.w = __uint_as_float((unsigned)(unsigned short)kv[3] << 16);
        acc += a * kf;
    }
    *(f32x4*)&cpart[(size_t)(b * 32 + scn) * HDIM + t * 4] = acc;
}

__global__ __launch_bounds__(256) void k_ctxred(const float* __restrict__ cpart,
                                                float* __restrict__ ctx){
    int idx = blockIdx.x * 256 + threadIdx.x;   // 128 blocks
    int b = idx >> 10, h = idx & 1023;
    float s = 0.f;
#pragma unroll
    for (int sc = 0; sc < 32; ++sc)
        s += cpart[(size_t)(b * 32 + sc) * HDIM + h];
    ctx[idx] = s;
}

// ---------------- launch ---------------------------------------------------------
extern "C" void kernel_launch(void* const* d_in, const int* in_sizes, int n_in,
                              void* d_out, int out_size, void* d_ws, size_t ws_size,
                              hipStream_t stream){
    (void)in_sizes; (void)n_in; (void)out_size; (void)ws_size;
    const float* query = (const float*)d_in[0];
    const float* keys  = (const float*)d_in[1];
    const int*   mask  = (const int*)d_in[2];
    const float* W1    = (const float*)d_in[3];
    const float* W2    = (const float*)d_in[4];
    const float* V     = (const float*)d_in[5];

    float* ctx_out  = (float*)d_out;            // [32][1024]
    float* attn_out = ctx_out + BATCH * HDIM;   // [32][2048]

    char* ws = (char*)d_ws;
    u16*   W1T   = (u16*)ws;                                   // 2 MB
    float* qproj = (float*)(ws + (2u << 20));                  // 128 KB
    float* spart = (float*)(ws + (2u << 20) + (128u << 10));   // 4 MB
    float* cpart = spart;   // ctxpart partials reuse spart (dead after softmax)
    u16*   keysbf= (u16*)(ws + (9u << 20));                    // 128 MB

    k_w1t    <<<dim3(256),  dim3(256), 0, stream>>>(W1, W1T);
    k_qproj  <<<dim3(512),  dim3(256), 0, stream>>>(query, W2, qproj);
    k_cvt    <<<dim3(2048), dim3(256), 0, stream>>>(keys, keysbf);
    k_score  <<<dim3(1024), dim3(512), 0, stream>>>(keysbf, W1T, qproj, V, spart);
    k_softmax<<<dim3(32),   dim3(256), 0, stream>>>(spart, mask, attn_out);
    k_ctxpart<<<dim3(1024), dim3(256), 0, stream>>>(keysbf, attn_out, cpart);
    k_ctxred <<<dim3(128),  dim3(256), 0, stream>>>(cpart, ctx_out);
}

// Round 11
// 202.890 us; speedup vs baseline: 1.5064x; 1.5064x over previous
//
#include <hip/hip_runtime.h>

typedef float  f32x4 __attribute__((ext_vector_type(4)));
typedef short  s16x8 __attribute__((ext_vector_type(8)));
typedef short  s16x4 __attribute__((ext_vector_type(4)));
typedef unsigned short u16;

#define HDIM 1024
#define BATCH 32
#define SEQ 2048
#define NROWS (BATCH*SEQ)   // 65536

// k_score: 256x256 tile, BK=32, 8 waves (2M x 4N), 512 threads (R3 champion)
#define BM 256
#define BN 256
#define BK 32
#define NKT (HDIM/BK)       // 32

#define GLD16(gp, lp) __builtin_amdgcn_global_load_lds( \
    (const __attribute__((address_space(1))) void*)(gp), \
    (__attribute__((address_space(3))) void*)(lp), 16, 0, 0)

#define VMCNT(n) asm volatile("s_waitcnt vmcnt(" #n ")" ::: "memory")
#define LGKM0    asm volatile("s_waitcnt lgkmcnt(0)" ::: "memory")
#define BARRIER  asm volatile("s_barrier" ::: "memory")
#define SCHEDB   __builtin_amdgcn_sched_barrier(0)

__device__ __forceinline__ u16 f2bf(float f){
    unsigned u = __float_as_uint(f);
    u = u + 0x7FFFu + ((u >> 16) & 1u);   // RNE
    return (u16)(u >> 16);
}

__device__ __forceinline__ float tanh_fast(float x){
    float e = __builtin_amdgcn_exp2f(x * 2.885390082f);
    return 1.0f - 2.0f * __builtin_amdgcn_rcpf(e + 1.0f);
}

// ---------------- mask compaction: cnt[b], idx (compact->orig), pos (orig->cmp) --
__global__ __launch_bounds__(256) void k_mask(const int* __restrict__ mask,
                                              int* __restrict__ cnt,
                                              int* __restrict__ idx,
                                              int* __restrict__ pos){
    int b = blockIdx.x, t = threadIdx.x;
    const int* mb = mask + (size_t)b * SEQ;
    int f[8], s = 0;
#pragma unroll
    for (int i = 0; i < 8; ++i){ f[i] = (mb[t * 8 + i] != 0); s += f[i]; }
    __shared__ int ps[256];
    ps[t] = s;
    __syncthreads();
    for (int off = 1; off < 256; off <<= 1){
        int v = (t >= off) ? ps[t - off] : 0;
        __syncthreads();
        ps[t] += v;
        __syncthreads();
    }
    int run = ps[t] - s;                 // exclusive prefix for this thread
    if (t == 255) cnt[b] = ps[255];
#pragma unroll
    for (int i = 0; i < 8; ++i){
        int so = t * 8 + i;
        if (f[i]){
            idx[(size_t)b * SEQ + run] = so;
            pos[(size_t)b * SEQ + so]  = run;
            ++run;
        }
    }
}

// ---------------- gather-convert unmasked keys fp32 -> compact bf16 --------------
// grid 8192 = 32 b x 256 chunks; 256 thr = 8 rows x 32 lanes; 512B coalesced reads
__global__ __launch_bounds__(256) void k_gather(const float* __restrict__ keys,
                                                const int* __restrict__ cnt,
                                                const int* __restrict__ idx,
                                                u16* __restrict__ keysbf){
    int blk = blockIdx.x;
    int b = blk >> 8, chunk = blk & 255;
    int n = cnt[b];
    int base = chunk * 8;
    if (base >= n) return;
    int t = threadIdx.x;
    int j = t >> 5, l = t & 31;
    int slot = base + j;
    if (slot >= n) return;               // no barriers below: divergence safe
    int orig = idx[(size_t)b * SEQ + slot];
    const float* src = keys + ((size_t)b * SEQ + orig) * HDIM + l * 4;
    u16* dst = keysbf + ((size_t)b * SEQ + slot) * HDIM + l * 4;
#pragma unroll
    for (int i = 0; i < 8; ++i){
        f32x4 v = *(const f32x4*)(src + i * 128);
        s16x4 o;
        o[0] = (short)f2bf(v.x); o[1] = (short)f2bf(v.y);
        o[2] = (short)f2bf(v.z); o[3] = (short)f2bf(v.w);
        *(s16x4*)(dst + i * 128) = o;
    }
}

// ---------------- W1 -> W1T (bf16, transposed) -----------------------------------
__global__ __launch_bounds__(256) void k_w1t(const float* __restrict__ W1,
                                             u16* __restrict__ W1T){
    __shared__ u16 t[64][65];
    int blk = blockIdx.x;
    int bh = blk >> 4, bd = blk & 15;
    int h0 = bh * 64, d0 = bd * 64;
    int tid = threadIdx.x;
    int lh = tid >> 4, ld = (tid & 15) * 4;
#pragma unroll
    for (int i = 0; i < 4; ++i){
        int hh = lh + i * 16;
        f32x4 v = *(const f32x4*)&W1[(size_t)(h0 + hh) * HDIM + d0 + ld];
        t[hh][ld + 0] = f2bf(v.x);
        t[hh][ld + 1] = f2bf(v.y);
        t[hh][ld + 2] = f2bf(v.z);
        t[hh][ld + 3] = f2bf(v.w);
    }
    __syncthreads();
    int wv = tid >> 6, ln = tid & 63;
#pragma unroll
    for (int i = 0; i < 16; ++i){
        int d = i * 4 + wv;
        W1T[(size_t)(d0 + d) * HDIM + h0 + ln] = t[ln][d];
    }
}

// ---------------- qproj: 512 blocks, 4 h-quarter partials + LDS reduce -----------
__global__ __launch_bounds__(256) void k_qproj(const float* __restrict__ query,
                                               const float* __restrict__ W2,
                                               float* __restrict__ qproj){
    int b = blockIdx.x >> 4, dc = blockIdx.x & 15;
    int t = threadIdx.x;
    int dl = t & 63, hq = t >> 6;
    int d = dc * 64 + dl;
    const float* q = query + (size_t)b * HDIM;
    float acc = 0.f;
#pragma unroll 8
    for (int h = hq * 256; h < hq * 256 + 256; ++h)
        acc += q[h] * W2[(size_t)h * HDIM + d];
    __shared__ float red[4][64];
    red[hq][dl] = acc;
    __syncthreads();
    if (hq == 0)
        qproj[(size_t)b * HDIM + d] = red[0][dl] + red[1][dl] + red[2][dl] + red[3][dl];
}

// ---------------- scores GEMM: R3 champion (173 us) + masked-tile early exit -----
// Compact rows per batch: only tiles with (mt&7)*256 < cnt[b] do work. Garbage
// rows in the boundary tile are computed but never read (softmax uses pos<cnt).
__global__ __launch_bounds__(512, 2) void k_score(const u16* __restrict__ keysbf,
                                                  const u16* __restrict__ W1T,
                                                  const float* __restrict__ qproj,
                                                  const float* __restrict__ V,
                                                  const int* __restrict__ cnt,
                                                  float* __restrict__ spart){
    int bid = blockIdx.x;
    int lid = (bid & 7) * 128 + (bid >> 3);   // XCD swizzle; 4 nt of one mt per XCD
    int mt  = lid >> 2;           // 0..255
    int nt  = lid & 3;            // 0..3
    int b_idx = mt >> 3;
    if ((mt & 7) * 256 >= cnt[b_idx]) return;   // uniform: whole tile masked out

    __shared__ u16 As[2][BM * BK];   // 16 KB per buf
    __shared__ u16 Bs[2][BM * BK];

    int tid  = threadIdx.x;
    int lane = tid & 63, wave = tid >> 6;
    int wm = wave >> 2, wn = wave & 3;
    int g  = lane >> 4, q = lane & 15;

    int sr = tid >> 2, sl = tid & 3;
    int ch = sl ^ ((sr >> 1) & 3);            // pre-swizzled global 16B chunk
    const u16* asrc = keysbf + (size_t)(mt * BM + sr) * HDIM + ch * 8;
    const u16* bsrc = W1T    + (size_t)(nt * BN + sr) * HDIM + ch * 8;
    int dst = tid * 8;

    auto stage = [&](int buf, int kt){
        int ko = kt * BK;
        GLD16(asrc + ko,               &As[buf][dst]);
        GLD16(asrc + ko + 128 * HDIM,  &As[buf][dst + 128 * BK]);
        GLD16(bsrc + ko,               &Bs[buf][dst]);
        GLD16(bsrc + ko + 128 * HDIM,  &Bs[buf][dst + 128 * BK]);
    };

    int slotx = (q >> 1) & 3;
    int rslot = (g ^ slotx) * 8;
    int aoff = (wm * 128 + q) * BK + rslot;
    int boff = (wn * 64 + q) * BK + rslot;

    f32x4 acc[8][4];
#pragma unroll
    for (int m = 0; m < 8; ++m)
#pragma unroll
        for (int n = 0; n < 4; ++n) acc[m][n] = 0.f;

    stage(0, 0);
    stage(1, 1);
    VMCNT(4);
    SCHEDB;
    BARRIER;
    SCHEDB;

    for (int kt = 0; kt < NKT; ++kt){
        int cur = kt & 1;
        s16x8 af[8], bq[4];
#pragma unroll
        for (int m = 0; m < 8; ++m) af[m] = *(const s16x8*)&As[cur][aoff + m * 16 * BK];
#pragma unroll
        for (int n = 0; n < 4; ++n) bq[n] = *(const s16x8*)&Bs[cur][boff + n * 16 * BK];

        __builtin_amdgcn_s_setprio(1);
#pragma unroll
        for (int m = 0; m < 8; ++m)
#pragma unroll
            for (int n = 0; n < 4; ++n)
                acc[m][n] = __builtin_amdgcn_mfma_f32_16x16x32_bf16(af[m], bq[n], acc[m][n], 0, 0, 0);
        __builtin_amdgcn_s_setprio(0);

        SCHEDB;
        LGKM0;
        BARRIER;
        SCHEDB;
        stage(cur, (kt + 2 < NKT) ? kt + 2 : NKT - 1);
        VMCNT(4);
        SCHEDB;
        BARRIER;
        SCHEDB;
    }
    VMCNT(0);

    float Vn[4], Qn[4];
#pragma unroll
    for (int n = 0; n < 4; ++n){
        int D = nt * BN + wn * 64 + n * 16 + q;
        Vn[n] = V[D];
        Qn[n] = qproj[(size_t)b_idx * HDIM + D];
    }
#pragma unroll
    for (int m = 0; m < 8; ++m){
#pragma unroll
        for (int r = 0; r < 4; ++r){
            float s = 0.f;
#pragma unroll
            for (int n = 0; n < 4; ++n){
                float x = acc[m][n][r] + Qn[n];
                s += Vn[n] * tanh_fast(x);
            }
            s += __shfl_xor(s, 1);
            s += __shfl_xor(s, 2);
            s += __shfl_xor(s, 4);
            s += __shfl_xor(s, 8);
            if (q == 0){
                int R = mt * BM + wm * 128 + m * 16 + g * 4 + r;   // compact row
                spart[(size_t)R * 16 + nt * 4 + wn] = s;
            }
        }
    }
}

// ---------------- softmax over S per batch (gathers compact spart via pos) -------
__global__ __launch_bounds__(256) void k_softmax(const float* __restrict__ spart,
                                                 const int* __restrict__ mask,
                                                 const int* __restrict__ pos,
                                                 float* __restrict__ attn){
    int b = blockIdx.x;
    int tid = threadIdx.x;
    int lane = tid & 63, wv = tid >> 6;
    __shared__ float redmx[4];
    __shared__ float redsm[4];

    float sc[8];
#pragma unroll
    for (int i = 0; i < 8; ++i){
        int s = i * 256 + tid;
        int mk = mask[(size_t)b * SEQ + s];
        if (mk != 0){
            int p = pos[(size_t)b * SEQ + s];    // valid (0..cnt-1) when unmasked
            const f32x4* pp = (const f32x4*)&spart[((size_t)b * SEQ + p) * 16];
            f32x4 v0 = pp[0], v1 = pp[1], v2 = pp[2], v3 = pp[3];
            sc[i] = (v0.x + v0.y + v0.z + v0.w) + (v1.x + v1.y + v1.z + v1.w)
                  + (v2.x + v2.y + v2.z + v2.w) + (v3.x + v3.y + v3.z + v3.w);
        } else {
            sc[i] = -1e9f;
        }
    }
    float mx = sc[0];
#pragma unroll
    for (int i = 1; i < 8; ++i) mx = fmaxf(mx, sc[i]);
#pragma unroll
    for (int o = 32; o >= 1; o >>= 1) mx = fmaxf(mx, __shfl_xor(mx, o));
    if (lane == 0) redmx[wv] = mx;
    __syncthreads();
    mx = fmaxf(fmaxf(redmx[0], redmx[1]), fmaxf(redmx[2], redmx[3]));

    float ex[8], ssum = 0.f;
#pragma unroll
    for (int i = 0; i < 8; ++i){
        ex[i] = __builtin_amdgcn_exp2f((sc[i] - mx) * 1.4426950408889634f);
        ssum += ex[i];
    }
#pragma unroll
    for (int o = 32; o >= 1; o >>= 1) ssum += __shfl_xor(ssum, o);
    if (lane == 0) redsm[wv] = ssum;
    __syncthreads();
    ssum = redsm[0] + redsm[1] + redsm[2] + redsm[3];
    float inv = 1.0f / ssum;
#pragma unroll
    for (int i = 0; i < 8; ++i)
        attn[(size_t)b * SEQ + i * 256 + tid] = ex[i] * inv;
}

// ---------------- context partials over compact rows: cpart[b][32][h] ------------
__global__ __launch_bounds__(256) void k_ctxpart(const u16* __restrict__ keysbf,
                                                 const float* __restrict__ attn,
                                                 const int* __restrict__ cnt,
                                                 const int* __restrict__ idx,
                                                 float* __restrict__ cpart){
    int blk = blockIdx.x;                 // 1024 blocks
    int b = blk >> 5, scn = blk & 31;     // 64 compact slots each
    int t = threadIdx.x;
    int n = cnt[b];
    int lim = n - scn * 64;
    if (lim > 64) lim = 64;
    f32x4 acc = 0.f;
    const s16x4* kp = (const s16x4*)(keysbf + (size_t)(b * SEQ + scn * 64) * HDIM) + t;
    const int* ip = idx + (size_t)b * SEQ + scn * 64;
    const float* ab = attn + (size_t)b * SEQ;
    for (int s = 0; s < lim; ++s){
        float a = ab[ip[s]];
        s16x4 kv = kp[(size_t)s * 256];
        f32x4 kf;
        kf.x = __uint_as_float((unsigned)(unsigned short)kv[0] << 16);
        kf.y = __uint_as_float((unsigned)(unsigned short)kv[1] << 16);
        kf.z = __uint_as_float((unsigned)(unsigned short)kv[2] << 16);
        kf.w = __uint_as_float((unsigned)(unsigned short)kv[3] << 16);
        acc += a * kf;
    }
    // always write (zeros when lim<=0) so ctxred sums no garbage
    *(f32x4*)&cpart[(size_t)(b * 32 + scn) * HDIM + t * 4] = acc;
}

__global__ __launch_bounds__(256) void k_ctxred(const float* __restrict__ cpart,
                                                float* __restrict__ ctx){
    int idx = blockIdx.x * 256 + threadIdx.x;   // 128 blocks
    int b = idx >> 10, h = idx & 1023;
    float s = 0.f;
#pragma unroll
    for (int sc = 0; sc < 32; ++sc)
        s += cpart[(size_t)(b * 32 + sc) * HDIM + h];
    ctx[idx] = s;
}

// ---------------- launch ---------------------------------------------------------
extern "C" void kernel_launch(void* const* d_in, const int* in_sizes, int n_in,
                              void* d_out, int out_size, void* d_ws, size_t ws_size,
                              hipStream_t stream){
    (void)in_sizes; (void)n_in; (void)out_size; (void)ws_size;
    const float* query = (const float*)d_in[0];
    const float* keys  = (const float*)d_in[1];
    const int*   mask  = (const int*)d_in[2];
    const float* W1    = (const float*)d_in[3];
    const float* W2    = (const float*)d_in[4];
    const float* V     = (const float*)d_in[5];

    float* ctx_out  = (float*)d_out;            // [32][1024]
    float* attn_out = ctx_out + BATCH * HDIM;   // [32][2048]

    char* ws = (char*)d_ws;
    u16*   W1T   = (u16*)ws;                                   // 2 MB   @ 0
    float* qproj = (float*)(ws + (2u << 20));                  // 128 KB @ 2M
    int*   cnt   = (int*)  (ws + (2u << 20) + (256u << 10));   // 128 B
    int*   idx   = (int*)  (ws + (2u << 20) + (512u << 10));   // 256 KB @ 2.5M
    int*   pos   = (int*)  (ws + (3u << 20));                  // 256 KB @ 3M
    float* spart = (float*)(ws + (4u << 20));                  // 4 MB   @ 4M
    float* cpart = spart;   // reuse (spart dead after softmax)
    u16*   keysbf= (u16*)(ws + (9u << 20));                    // 128 MB @ 9M

    k_w1t    <<<dim3(256),  dim3(256), 0, stream>>>(W1, W1T);
    k_qproj  <<<dim3(512),  dim3(256), 0, stream>>>(query, W2, qproj);
    k_mask   <<<dim3(32),   dim3(256), 0, stream>>>(mask, cnt, idx, pos);
    k_gather <<<dim3(8192), dim3(256), 0, stream>>>(keys, cnt, idx, keysbf);
    k_score  <<<dim3(1024), dim3(512), 0, stream>>>(keysbf, W1T, qproj, V, cnt, spart);
    k_softmax<<<dim3(32),   dim3(256), 0, stream>>>(spart, mask, pos, attn_out);
    k_ctxpart<<<dim3(1024), dim3(256), 0, stream>>>(keysbf, attn_out, cnt, idx, cpart);
    k_ctxred <<<dim3(128),  dim3(256), 0, stream>>>(cpart, ctx_out);
}

// Round 12
// 196.641 us; speedup vs baseline: 1.5542x; 1.0318x over previous
//
#include <hip/hip_runtime.h>

typedef float  f32x4 __attribute__((ext_vector_type(4)));
typedef int    i32x4 __attribute__((ext_vector_type(4)));
typedef short  s16x8 __attribute__((ext_vector_type(8)));
typedef short  s16x4 __attribute__((ext_vector_type(4)));
typedef unsigned short u16;

#define HDIM 1024
#define BATCH 32
#define SEQ 2048
#define NROWS (BATCH*SEQ)   // 65536
#define GSEQ 8192           // 4 batches per compaction group
#define NGRP 8

// k_score: 256x256 tile, BK=32, 8 waves (2M x 4N), 512 threads (R3 champion)
#define BM 256
#define BN 256
#define BK 32
#define NKT (HDIM/BK)       // 32

#define GLD16(gp, lp) __builtin_amdgcn_global_load_lds( \
    (const __attribute__((address_space(1))) void*)(gp), \
    (__attribute__((address_space(3))) void*)(lp), 16, 0, 0)

#define VMCNT(n) asm volatile("s_waitcnt vmcnt(" #n ")" ::: "memory")
#define LGKM0    asm volatile("s_waitcnt lgkmcnt(0)" ::: "memory")
#define BARRIER  asm volatile("s_barrier" ::: "memory")
#define SCHEDB   __builtin_amdgcn_sched_barrier(0)

__device__ __forceinline__ u16 f2bf(float f){
    unsigned u = __float_as_uint(f);
    u = u + 0x7FFFu + ((u >> 16) & 1u);   // RNE
    return (u16)(u >> 16);
}

__device__ __forceinline__ float tanh_fast(float x){
    float e = __builtin_amdgcn_exp2f(x * 2.885390082f);
    return 1.0f - 2.0f * __builtin_amdgcn_rcpf(e + 1.0f);
}

// ---------------- setup: W1T transpose | qproj | mask group-scan -----------------
// blocks [0,256) w1t; [256,768) qproj; [768,776) mask scan (1 per 4-batch group).
__global__ __launch_bounds__(256) void k_setup(const float* __restrict__ W1,
                                               u16* __restrict__ W1T,
                                               const float* __restrict__ query,
                                               const float* __restrict__ W2,
                                               float* __restrict__ qproj,
                                               const int* __restrict__ mask,
                                               int* __restrict__ cnt4,
                                               int* __restrict__ off,
                                               int* __restrict__ idx,
                                               int* __restrict__ pos){
    __shared__ u16 tsh[64][65];
    __shared__ float red[4][64];
    __shared__ int ps[256];
    int blk = blockIdx.x;
    int tid = threadIdx.x;

    if (blk < 256){
        // ---- W1 -> W1T (bf16, transposed) ----
        int bh = blk >> 4, bd = blk & 15;
        int h0 = bh * 64, d0 = bd * 64;
        int lh = tid >> 4, ld = (tid & 15) * 4;
#pragma unroll
        for (int i = 0; i < 4; ++i){
            int hh = lh + i * 16;
            f32x4 v = *(const f32x4*)&W1[(size_t)(h0 + hh) * HDIM + d0 + ld];
            tsh[hh][ld + 0] = f2bf(v.x);
            tsh[hh][ld + 1] = f2bf(v.y);
            tsh[hh][ld + 2] = f2bf(v.z);
            tsh[hh][ld + 3] = f2bf(v.w);
        }
        __syncthreads();
        int wv = tid >> 6, ln = tid & 63;
#pragma unroll
        for (int i = 0; i < 16; ++i){
            int d = i * 4 + wv;
            W1T[(size_t)(d0 + d) * HDIM + h0 + ln] = tsh[ln][d];
        }
    } else if (blk < 768){
        // ---- qproj[b][d] = sum_h query[b][h] * W2[h][d] ----
        int blk2 = blk - 256;
        int b = blk2 >> 4, dc = blk2 & 15;
        int dl = tid & 63, hq = tid >> 6;
        int d = dc * 64 + dl;
        const float* q = query + (size_t)b * HDIM;
        float acc = 0.f;
#pragma unroll 8
        for (int h = hq * 256; h < hq * 256 + 256; ++h)
            acc += q[h] * W2[(size_t)h * HDIM + d];
        red[hq][dl] = acc;
        __syncthreads();
        if (hq == 0)
            qproj[(size_t)b * HDIM + d] = red[0][dl] + red[1][dl] + red[2][dl] + red[3][dl];
    } else {
        // ---- mask scan for group g: cnt4, off[4], idx (cmp->orig), pos ----
        int g = blk - 768;
        const int* mb = mask + (size_t)g * GSEQ;
        unsigned bits = 0;
#pragma unroll
        for (int i = 0; i < 8; ++i){
            i32x4 v = ((const i32x4*)mb)[tid * 8 + i];
            bits |= (unsigned)(v.x != 0) << (i * 4 + 0);
            bits |= (unsigned)(v.y != 0) << (i * 4 + 1);
            bits |= (unsigned)(v.z != 0) << (i * 4 + 2);
            bits |= (unsigned)(v.w != 0) << (i * 4 + 3);
        }
        int s = __popc(bits);
        ps[tid] = s;
        __syncthreads();
        for (int o = 1; o < 256; o <<= 1){
            int v = (tid >= o) ? ps[tid - o] : 0;
            __syncthreads();
            ps[tid] += v;
            __syncthreads();
        }
        int run = ps[tid] - s;               // exclusive prefix at elem tid*32
        if (tid == 255) cnt4[g] = ps[255];
        if ((tid & 63) == 0) off[g * 4 + (tid >> 6)] = run;   // batch starts at 2048j
        for (int i = 0; i < 32; ++i){
            if ((bits >> i) & 1u){
                int slot = run + __popc(bits & ((1u << i) - 1u));
                int so = tid * 32 + i;
                idx[(size_t)g * GSEQ + slot] = so;
                pos[(size_t)g * GSEQ + so]  = slot;
            }
        }
    }
}

// ---------------- gather-convert unmasked keys fp32 -> group-compact bf16 --------
__global__ __launch_bounds__(256) void k_gather(const float* __restrict__ keys,
                                                const int* __restrict__ cnt4,
                                                const int* __restrict__ idx,
                                                u16* __restrict__ keysbf){
    int blk = blockIdx.x;                 // 8192 = 8 groups x 1024 chunks
    int g = blk >> 10, chunk = blk & 1023;
    int n = cnt4[g];
    int base = chunk * 8;
    if (base >= n) return;
    int t = threadIdx.x;
    int j = t >> 5, l = t & 31;
    int slot = base + j;
    if (slot >= n) return;                // no barriers below: divergence safe
    int orig = idx[(size_t)g * GSEQ + slot];
    const float* src = keys + ((size_t)g * GSEQ + orig) * HDIM + l * 4;
    u16* dst = keysbf + ((size_t)g * GSEQ + slot) * HDIM + l * 4;
#pragma unroll
    for (int i = 0; i < 8; ++i){
        f32x4 v = *(const f32x4*)(src + i * 128);
        s16x4 o;
        o[0] = (short)f2bf(v.x); o[1] = (short)f2bf(v.y);
        o[2] = (short)f2bf(v.z); o[3] = (short)f2bf(v.w);
        *(s16x4*)(dst + i * 128) = o;
    }
}

// ---------------- scores GEMM: R3 champion + group-compact early exit ------------
// Rows are group-compact (4 batches contiguous per group). Epilogue selects the
// per-row qproj bias by comparing the row's compact slot against the group's
// batch offsets (monotone step function; 3 cndmask per row).
__global__ __launch_bounds__(512, 2) void k_score(const u16* __restrict__ keysbf,
                                                  const u16* __restrict__ W1T,
                                                  const float* __restrict__ qproj,
                                                  const float* __restrict__ V,
                                                  const int* __restrict__ cnt4,
                                                  const int* __restrict__ off,
                                                  float* __restrict__ spart){
    int bid = blockIdx.x;
    int lid = (bid & 7) * 128 + (bid >> 3);   // XCD swizzle
    int gb  = lid >> 7;                        // group 0..7
    int r7  = lid & 127;
    int mtl = r7 >> 2;                         // 0..31 within group
    int nt  = r7 & 3;
    if (mtl * 256 >= cnt4[gb]) return;         // uniform: tile fully beyond cnt

    __shared__ u16 As[2][BM * BK];
    __shared__ u16 Bs[2][BM * BK];

    int tid  = threadIdx.x;
    int lane = tid & 63, wave = tid >> 6;
    int wm = wave >> 2, wn = wave & 3;
    int lg = lane >> 4, q = lane & 15;

    int sr = tid >> 2, sl = tid & 3;
    int ch = sl ^ ((sr >> 1) & 3);
    const u16* asrc = keysbf + ((size_t)gb * GSEQ + mtl * BM + sr) * HDIM + ch * 8;
    const u16* bsrc = W1T    + (size_t)(nt * BN + sr) * HDIM + ch * 8;
    int dst = tid * 8;

    auto stage = [&](int buf, int kt){
        int ko = kt * BK;
        GLD16(asrc + ko,               &As[buf][dst]);
        GLD16(asrc + ko + 128 * HDIM,  &As[buf][dst + 128 * BK]);
        GLD16(bsrc + ko,               &Bs[buf][dst]);
        GLD16(bsrc + ko + 128 * HDIM,  &Bs[buf][dst + 128 * BK]);
    };

    int slotx = (q >> 1) & 3;
    int rslot = (lg ^ slotx) * 8;
    int aoff = (wm * 128 + q) * BK + rslot;
    int boff = (wn * 64 + q) * BK + rslot;

    f32x4 acc[8][4];
#pragma unroll
    for (int m = 0; m < 8; ++m)
#pragma unroll
        for (int n = 0; n < 4; ++n) acc[m][n] = 0.f;

    stage(0, 0);
    stage(1, 1);
    VMCNT(4);
    SCHEDB;
    BARRIER;
    SCHEDB;

    for (int kt = 0; kt < NKT; ++kt){
        int cur = kt & 1;
        s16x8 af[8], bq[4];
#pragma unroll
        for (int m = 0; m < 8; ++m) af[m] = *(const s16x8*)&As[cur][aoff + m * 16 * BK];
#pragma unroll
        for (int n = 0; n < 4; ++n) bq[n] = *(const s16x8*)&Bs[cur][boff + n * 16 * BK];

        __builtin_amdgcn_s_setprio(1);
#pragma unroll
        for (int m = 0; m < 8; ++m)
#pragma unroll
            for (int n = 0; n < 4; ++n)
                acc[m][n] = __builtin_amdgcn_mfma_f32_16x16x32_bf16(af[m], bq[n], acc[m][n], 0, 0, 0);
        __builtin_amdgcn_s_setprio(0);

        SCHEDB;
        LGKM0;
        BARRIER;
        SCHEDB;
        stage(cur, (kt + 2 < NKT) ? kt + 2 : NKT - 1);
        VMCNT(4);
        SCHEDB;
        BARRIER;
        SCHEDB;
    }
    VMCNT(0);

    // ---- epilogue with per-row batch-select qproj ----
    int o1 = off[gb * 4 + 1], o2 = off[gb * 4 + 2], o3 = off[gb * 4 + 3];
    float Vn[4], Q0[4], Q1[4], Q2[4], Q3[4];
#pragma unroll
    for (int n = 0; n < 4; ++n){
        int D = nt * BN + wn * 64 + n * 16 + q;
        Vn[n] = V[D];
        Q0[n] = qproj[(size_t)(gb * 4 + 0) * HDIM + D];
        Q1[n] = qproj[(size_t)(gb * 4 + 1) * HDIM + D];
        Q2[n] = qproj[(size_t)(gb * 4 + 2) * HDIM + D];
        Q3[n] = qproj[(size_t)(gb * 4 + 3) * HDIM + D];
    }
#pragma unroll
    for (int m = 0; m < 8; ++m){
#pragma unroll
        for (int r = 0; r < 4; ++r){
            int loc = mtl * BM + wm * 128 + m * 16 + lg * 4 + r;  // compact slot
            float s = 0.f;
#pragma unroll
            for (int n = 0; n < 4; ++n){
                float Qn = Q0[n];
                Qn = (loc >= o1) ? Q1[n] : Qn;
                Qn = (loc >= o2) ? Q2[n] : Qn;
                Qn = (loc >= o3) ? Q3[n] : Qn;
                float x = acc[m][n][r] + Qn;
                s += Vn[n] * tanh_fast(x);
            }
            s += __shfl_xor(s, 1);
            s += __shfl_xor(s, 2);
            s += __shfl_xor(s, 4);
            s += __shfl_xor(s, 8);
            if (q == 0)
                spart[((size_t)gb * GSEQ + loc) * 16 + nt * 4 + wn] = s;
        }
    }
}

// ---------------- softmax over S per batch (gathers group-compact spart) ---------
__global__ __launch_bounds__(256) void k_softmax(const float* __restrict__ spart,
                                                 const int* __restrict__ mask,
                                                 const int* __restrict__ pos,
                                                 float* __restrict__ attn){
    int b = blockIdx.x;
    int gb = b >> 2;
    int tid = threadIdx.x;
    int lane = tid & 63, wv = tid >> 6;
    __shared__ float redmx[4];
    __shared__ float redsm[4];

    float sc[8];
#pragma unroll
    for (int i = 0; i < 8; ++i){
        int s = i * 256 + tid;
        int mk = mask[(size_t)b * SEQ + s];
        if (mk != 0){
            int p = pos[(size_t)b * SEQ + s];    // slot within group
            const f32x4* pp = (const f32x4*)&spart[((size_t)gb * GSEQ + p) * 16];
            f32x4 v0 = pp[0], v1 = pp[1], v2 = pp[2], v3 = pp[3];
            sc[i] = (v0.x + v0.y + v0.z + v0.w) + (v1.x + v1.y + v1.z + v1.w)
                  + (v2.x + v2.y + v2.z + v2.w) + (v3.x + v3.y + v3.z + v3.w);
        } else {
            sc[i] = -1e9f;
        }
    }
    float mx = sc[0];
#pragma unroll
    for (int i = 1; i < 8; ++i) mx = fmaxf(mx, sc[i]);
#pragma unroll
    for (int o = 32; o >= 1; o >>= 1) mx = fmaxf(mx, __shfl_xor(mx, o));
    if (lane == 0) redmx[wv] = mx;
    __syncthreads();
    mx = fmaxf(fmaxf(redmx[0], redmx[1]), fmaxf(redmx[2], redmx[3]));

    float ex[8], ssum = 0.f;
#pragma unroll
    for (int i = 0; i < 8; ++i){
        ex[i] = __builtin_amdgcn_exp2f((sc[i] - mx) * 1.4426950408889634f);
        ssum += ex[i];
    }
#pragma unroll
    for (int o = 32; o >= 1; o >>= 1) ssum += __shfl_xor(ssum, o);
    if (lane == 0) redsm[wv] = ssum;
    __syncthreads();
    ssum = redsm[0] + redsm[1] + redsm[2] + redsm[3];
    float inv = 1.0f / ssum;
#pragma unroll
    for (int i = 0; i < 8; ++i)
        attn[(size_t)b * SEQ + i * 256 + tid] = ex[i] * inv;
}

// ---------------- context partials over this batch's compact span ----------------
__global__ __launch_bounds__(256) void k_ctxpart(const u16* __restrict__ keysbf,
                                                 const float* __restrict__ attn,
                                                 const int* __restrict__ cnt4,
                                                 const int* __restrict__ off,
                                                 const int* __restrict__ idx,
                                                 float* __restrict__ cpart){
    int blk = blockIdx.x;                 // 1024 = 32 b x 32 slices
    int b = blk >> 5, scn = blk & 31;
    int gb = b >> 2, j = b & 3;
    int oj  = off[gb * 4 + j];
    int oj1 = (j < 3) ? off[gb * 4 + j + 1] : cnt4[gb];
    int nb  = oj1 - oj;                   // rows of this batch
    int lim = nb - scn * 64;
    if (lim > 64) lim = 64;
    int t = threadIdx.x;
    f32x4 acc = 0.f;
    size_t base = (size_t)gb * GSEQ + oj + scn * 64;
    const s16x4* kp = (const s16x4*)(keysbf + base * HDIM) + t;
    const int* ip = idx + base;
    const float* ab = attn;               // flat [b][s] == group row gb*GSEQ+idxv
    for (int s = 0; s < lim; ++s){
        float a = ab[(size_t)gb * GSEQ + ip[s]];
        s16x4 kv = kp[(size_t)s * 256];
        f32x4 kf;
        kf.x = __uint_as_float((unsigned)(unsigned short)kv[0] << 16);
        kf.y = __uint_as_float((unsigned)(unsigned short)kv[1] << 16);
        kf.z = __uint_as_float((unsigned)(unsigned short)kv[2] << 16);
        kf.w = __uint_as_float((unsigned)(unsigned short)kv[3] << 16);
        acc += a * kf;
    }
    // always write (zeros when lim<=0) so ctxred sums no garbage
    *(f32x4*)&cpart[(size_t)(b * 32 + scn) * HDIM + t * 4] = acc;
}

__global__ __launch_bounds__(256) void k_ctxred(const float* __restrict__ cpart,
                                                float* __restrict__ ctx){
    int id = blockIdx.x * 256 + threadIdx.x;   // 128 blocks
    int b = id >> 10, h = id & 1023;
    float s = 0.f;
#pragma unroll
    for (int sc = 0; sc < 32; ++sc)
        s += cpart[(size_t)(b * 32 + sc) * HDIM + h];
    ctx[id] = s;
}

// ---------------- launch ---------------------------------------------------------
extern "C" void kernel_launch(void* const* d_in, const int* in_sizes, int n_in,
                              void* d_out, int out_size, void* d_ws, size_t ws_size,
                              hipStream_t stream){
    (void)in_sizes; (void)n_in; (void)out_size; (void)ws_size;
    const float* query = (const float*)d_in[0];
    const float* keys  = (const float*)d_in[1];
    const int*   mask  = (const int*)d_in[2];
    const float* W1    = (const float*)d_in[3];
    const float* W2    = (const float*)d_in[4];
    const float* V     = (const float*)d_in[5];

    float* ctx_out  = (float*)d_out;            // [32][1024]
    float* attn_out = ctx_out + BATCH * HDIM;   // [32][2048]

    char* ws = (char*)d_ws;
    u16*   W1T   = (u16*)ws;                                   // 2 MB   @ 0
    float* qproj = (float*)(ws + (2u << 20));                  // 128 KB @ 2M
    int*   cnt4  = (int*)  (ws + (2u << 20) + (128u << 10));   // 32 B
    int*   off   = (int*)  (ws + (2u << 20) + (132u << 10));   // 128 B
    int*   idx   = (int*)  (ws + (2u << 20) + (512u << 10));   // 256 KB @ 2.5M
    int*   pos   = (int*)  (ws + (3u << 20));                  // 256 KB @ 3M
    float* spart = (float*)(ws + (4u << 20));                  // 4 MB   @ 4M
    float* cpart = spart;   // reuse (spart dead after softmax)
    u16*   keysbf= (u16*)(ws + (9u << 20));                    // 128 MB @ 9M

    k_setup  <<<dim3(776),  dim3(256), 0, stream>>>(W1, W1T, query, W2, qproj,
                                                    mask, cnt4, off, idx, pos);
    k_gather <<<dim3(8192), dim3(256), 0, stream>>>(keys, cnt4, idx, keysbf);
    k_score  <<<dim3(1024), dim3(512), 0, stream>>>(keysbf, W1T, qproj, V,
                                                    cnt4, off, spart);
    k_softmax<<<dim3(32),   dim3(256), 0, stream>>>(spart, mask, pos, attn_out);
    k_ctxpart<<<dim3(1024), dim3(256), 0, stream>>>(keysbf, attn_out, cnt4, off,
                                                    idx, cpart);
    k_ctxred <<<dim3(128),  dim3(256), 0, stream>>>(cpart, ctx_out);
}